// Round 10
// baseline (347.174 us; speedup 1.0000x reference)
//
#include <hip/hip_runtime.h>

// out[b,c] = mask[c] * (U @ X @ U^T),  U[n][h] = sum_k DH2[k][n]*DH[k][h]  (128x64)
// Stage 1: R = X @ U^T  (K=w, row-major X feeds MFMA A directly),
// Stage 2: out = U @ R  (K=h, R staged in LDS as [m][h] hi/lo fp16).
// fp16 2-term split (hi+lo), 3 MFMA passes -> ~2^-22 relative error.
// r10: slice split across 2 blocks along m (m-half per block):
//      LDS 37->18.4KB, grid 4096->8192, launch_bounds(256,8) -> <=64 VGPR,
//      8 blocks/CU = 32 waves/CU (2x TLP) to attack the latency bound.

typedef __attribute__((ext_vector_type(8))) _Float16 f16x8;
typedef __attribute__((ext_vector_type(4))) _Float16 f16x4;
typedef __attribute__((ext_vector_type(4))) float f32x4;

#define NBLOCKS 8192  // 4096 slices x 2 m-halves
#define MFMA16(A, B, C) __builtin_amdgcn_mfma_f32_16x16x32_f16((A), (B), (C), 0, 0, 0)

// ---------------------------------------------------------------------------
// Build U in MFMA fragment-dump order, fp16 hi/lo.
// Fragment (tile j=0..7, kk=0..1, hl=0..1) = 512 halfs; lane l holds 8 halfs:
//   value = U[16*j + (l&15)][32*kk + 8*(l>>4) + t],  t = 0..7
// Same table serves stage-1 B (by m-tile) and stage-2 A (by n-tile).
// ---------------------------------------------------------------------------
__global__ void build_ut(_Float16* __restrict__ uf) {
    const int idx = blockIdx.x * 256 + threadIdx.x;  // 0..8191
    const int n = idx >> 6;   // 0..127 (U row)
    const int h = idx & 63;   // 0..63  (U col)
    const float s0 = 0.125f;                 // sqrt(1/64)
    const float sk = 0.17677669529663687f;   // sqrt(2/64)
    const float t0 = 0.088388347648318447f;  // sqrt(1/128)
    const float tk = 0.125f;                 // sqrt(2/128)
    float acc = s0 * t0;
    #pragma unroll 4
    for (int k = 1; k < 64; ++k) {
        float a = cospif((float)((2 * h + 1) * k) * (1.0f / 128.0f));
        float b = cospif((float)((2 * n + 1) * k) * (1.0f / 256.0f));
        acc = fmaf(sk * tk * a, b, acc);
    }
    _Float16 hi = (_Float16)acc;
    _Float16 lo = (_Float16)(acc - (float)hi);
    const int j = n >> 4;
    const int lane = (n & 15) + 16 * ((h >> 3) & 3);
    const int kk = h >> 5;
    const int t = h & 7;
    const int base = ((j * 2 + kk) * 2) * 512 + lane * 8 + t;
    uf[base] = hi;         // hl = 0
    uf[base + 512] = lo;   // hl = 1
}

// ---------------------------------------------------------------------------
// One block = one (slice, m-half). 256 threads = 4 waves.
// Stage 1: R[h][m'] = sum_w X[h][w] * U[64*mh+m'][w]; wave wid owns h-tile wid,
//          j=0..3 local m-tiles (global m-tile 4*mh+j).
// Stage 2: out[n][64*mh+m'] = sum_h U[n][h] * R[h][m']; wave wid owns n-tiles
//          2*wid, 2*wid+1; j=0..3 local m-tiles.
// LDS: sRh/sRl [64][72] fp16 (pad 8 -> 2-way banks, aligned b128 reads) = 18.4KB
// -> 8 blocks/CU with <=64 VGPR (launch_bounds(256,8)) = 32 waves/CU.
// ---------------------------------------------------------------------------
__global__ __launch_bounds__(256, 8)
void dct_fsr(const float* __restrict__ x, const float* __restrict__ mask,
             const _Float16* __restrict__ uf, float* __restrict__ out) {
    __shared__ _Float16 sRh[64 * 72];
    __shared__ _Float16 sRl[64 * 72];

    const int tid = threadIdx.x;
    const int wid = tid >> 6;
    const int lane = tid & 63;
    const int l15 = lane & 15;
    const int lg = lane >> 4;  // 0..3
    const int bid = blockIdx.x;
    const int slice = bid >> 1;     // b*256 + c
    const int mh = bid & 1;         // m-half
    const float mval = mask[slice & 255];

    const f16x8* ufr = (const f16x8*)uf;  // [frag*64 + lane]

    // ---- A-frags for stage 1: X rows (16*wid + l15), 8 contiguous w per lane ----
    const float* xp = x + (size_t)slice * 4096 + (16 * wid + l15) * 64 + 8 * lg;
    const float4 xa = *(const float4*)xp;          // kk=0, t=0..3
    const float4 xb = *(const float4*)(xp + 4);    // kk=0, t=4..7
    const float4 xc = *(const float4*)(xp + 32);   // kk=1, t=0..3
    const float4 xd = *(const float4*)(xp + 36);   // kk=1, t=4..7

    f16x8 ah0, al0, ah1, al1;
#define SPLIT(H, L, E, V)                      \
    {                                          \
        float y_ = (V) * mval;                 \
        _Float16 h_ = (_Float16)y_;            \
        H[E] = h_;                             \
        L[E] = (_Float16)(y_ - (float)h_);     \
    }
    SPLIT(ah0, al0, 0, xa.x) SPLIT(ah0, al0, 1, xa.y)
    SPLIT(ah0, al0, 2, xa.z) SPLIT(ah0, al0, 3, xa.w)
    SPLIT(ah0, al0, 4, xb.x) SPLIT(ah0, al0, 5, xb.y)
    SPLIT(ah0, al0, 6, xb.z) SPLIT(ah0, al0, 7, xb.w)
    SPLIT(ah1, al1, 0, xc.x) SPLIT(ah1, al1, 1, xc.y)
    SPLIT(ah1, al1, 2, xc.z) SPLIT(ah1, al1, 3, xc.w)
    SPLIT(ah1, al1, 4, xd.x) SPLIT(ah1, al1, 5, xd.y)
    SPLIT(ah1, al1, 6, xd.z) SPLIT(ah1, al1, 7, xd.w)
#undef SPLIT

    // ---- stage 1: local m-tiles j=0..3 (global m-tile 4*mh+j) ----
    #pragma unroll
    for (int j = 0; j < 4; ++j) {
        const int jm = 4 * mh + j;
        const f16x8 bh0 = ufr[((jm * 2 + 0) * 2 + 0) * 64 + lane];
        const f16x8 bl0 = ufr[((jm * 2 + 0) * 2 + 1) * 64 + lane];
        const f16x8 bh1 = ufr[((jm * 2 + 1) * 2 + 0) * 64 + lane];
        const f16x8 bl1 = ufr[((jm * 2 + 1) * 2 + 1) * 64 + lane];
        f32x4 acc = {0.f, 0.f, 0.f, 0.f};
        acc = MFMA16(ah0, bh0, acc);
        acc = MFMA16(ah1, bh1, acc);
        acc = MFMA16(ah0, bl0, acc);
        acc = MFMA16(ah1, bl1, acc);
        acc = MFMA16(al0, bh0, acc);
        acc = MFMA16(al1, bh1, acc);
        // D frag: local col m' = 16j+l15, rows h = 16*wid + 4*lg + r -> sR[m'][h]
        const int m = 16 * j + l15;
        const int h0 = 16 * wid + 4 * lg;
        f16x4 rh, rl;
        #pragma unroll
        for (int r = 0; r < 4; ++r) {
            const float vv = acc[r];
            const _Float16 hi = (_Float16)vv;
            rh[r] = hi;
            rl[r] = (_Float16)(vv - (float)hi);
        }
        *(f16x4*)&sRh[m * 72 + h0] = rh;
        *(f16x4*)&sRl[m * 72 + h0] = rl;
    }

    // hoist i=0 stage-2 A-frags above the barrier (L2 latency overlaps wait)
    const int ig0 = 2 * wid;
    const f16x8 A0h0 = ufr[((ig0 * 2 + 0) * 2 + 0) * 64 + lane];
    const f16x8 A0l0 = ufr[((ig0 * 2 + 0) * 2 + 1) * 64 + lane];
    const f16x8 A0h1 = ufr[((ig0 * 2 + 1) * 2 + 0) * 64 + lane];
    const f16x8 A0l1 = ufr[((ig0 * 2 + 1) * 2 + 1) * 64 + lane];

    __syncthreads();

    // ---- stage 2: n-tiles ig = 2*wid + {0,1}, local m-tiles j=0..3 ----
    float* og = out + (size_t)slice * 16384 + 64 * mh;  // 128x128 slice, m-half
#define STAGE2(AH0, AL0, AH1, AL1, IG)                                   \
    {                                                                    \
        float* orow = og + (size_t)(16 * (IG) + 4 * lg) * 128 + l15;     \
        _Pragma("unroll")                                                \
        for (int j = 0; j < 4; ++j) {                                    \
            const int m = 16 * j + l15;                                  \
            const f16x8 bh0 = *(const f16x8*)&sRh[m * 72 + 0 + 8 * lg];  \
            const f16x8 bh1 = *(const f16x8*)&sRh[m * 72 + 32 + 8 * lg]; \
            const f16x8 bl0 = *(const f16x8*)&sRl[m * 72 + 0 + 8 * lg];  \
            const f16x8 bl1 = *(const f16x8*)&sRl[m * 72 + 32 + 8 * lg]; \
            f32x4 a = {0.f, 0.f, 0.f, 0.f};                              \
            a = MFMA16(AH0, bh0, a);                                     \
            a = MFMA16(AH1, bh1, a);                                     \
            a = MFMA16(AH0, bl0, a);                                     \
            a = MFMA16(AH1, bl1, a);                                     \
            a = MFMA16(AL0, bh0, a);                                     \
            a = MFMA16(AL1, bh1, a);                                     \
            _Pragma("unroll")                                            \
            for (int r = 0; r < 4; ++r)                                  \
                orow[(size_t)r * 128 + 16 * j] = a[r];                   \
        }                                                                \
    }

    STAGE2(A0h0, A0l0, A0h1, A0l1, ig0)

    {
        const int ig1 = 2 * wid + 1;
        const f16x8 A1h0 = ufr[((ig1 * 2 + 0) * 2 + 0) * 64 + lane];
        const f16x8 A1l0 = ufr[((ig1 * 2 + 0) * 2 + 1) * 64 + lane];
        const f16x8 A1h1 = ufr[((ig1 * 2 + 1) * 2 + 0) * 64 + lane];
        const f16x8 A1l1 = ufr[((ig1 * 2 + 1) * 2 + 1) * 64 + lane];
        STAGE2(A1h0, A1l0, A1h1, A1l1, ig1)
    }
#undef STAGE2
}

extern "C" void kernel_launch(void* const* d_in, const int* in_sizes, int n_in,
                              void* d_out, int out_size, void* d_ws, size_t ws_size,
                              hipStream_t stream) {
    const float* x = (const float*)d_in[0];      // [16,256,64,64] fp32
    const float* mask = (const float*)d_in[1];   // [1,256,1,1] fp32
    float* out = (float*)d_out;                  // [16,256,128,128] fp32
    _Float16* uf = (_Float16*)d_ws;              // 16384 halfs = 32KB

    build_ut<<<32, 256, 0, stream>>>(uf);
    dct_fsr<<<NBLOCKS, 256, 0, stream>>>(x, mask, uf, out);
}